// Round 6
// baseline (133.229 us; speedup 1.0000x reference)
//
#include <hip/hip_runtime.h>

#define CC 128
#define HH 56
#define WW 56
#define NK2 9
#define NO 18
#define WSZ 4
#define W64 64
#define NCG 16     // conv channel groups (8 ch each)
#define SCG 8      // sample channel groups (16 ch each)
#define CPG 16

// ws layout:
//  wsA : float [4*56][NCG][NO][W64]  = 16.5 MB
//  wsC : float4 [4][9][56][W64]      = 2.06 MB
//  wsI : uint   [4][9][56][W64]      = 0.52 MB
#define WSA_FLOATS (224L * NCG * NO * W64)
#define WSC_ENTRIES (4L * NK2 * HH * W64)

// ---------------- Kernel A: offset conv, 4 rows/block ----------------------
// block = (b, h4, cg: 8 channels); wave = 2 channels; weights transposed into
// LDS once per block, read back as wave-uniform float4 (broadcast ds_read_b128,
// conflict-free). 54 weights amortized over 4 output rows.
__global__ __launch_bounds__(256, 4) void conv_partial(
    const float* __restrict__ x,          // [B][C][H][W]
    const float* __restrict__ offset_w,   // [18][128][3][3]
    float* __restrict__ wsA)
{
    const int blk = blockIdx.x;           // (b*14 + h4)*16 + cg
    const int cg  = blk & 15;
    const int bh4 = blk >> 4;
    const int b   = bh4 / 14;
    const int h4  = bh4 - b * 14;
    const int h0  = h4 * 4;
    const int t   = threadIdx.x;
    const int lane = t & 63;
    const int wv  = __builtin_amdgcn_readfirstlane(t >> 6);   // 0..3

    __shared__ float s_wt[8][168];        // [cl][ky*56 + (o*3+kx)] 5.25 KiB
    __shared__ float s_red[4][NO][W64];   // 18 KiB

    // transpose this block's 8 channels of offset_w into LDS.
    // global idx for (o, cl, j): o*1152 + (cg*8+cl)*9 + j  (72 contiguous per o)
    const int c0 = cg * 8;
    for (int i = t; i < NO * 72; i += 256) {
        const int o   = i / 72;
        const int rem = i - o * 72;       // cl*9 + j
        const int cl  = rem / 9;
        const int j   = rem - cl * 9;     // ky*3 + kx
        const int ky  = j / 3, kx = j - ky * 3;
        s_wt[cl][ky * 56 + o * 3 + kx] = offset_w[o * (CC * 9) + (c0 + cl) * 9 + j];
    }
    __syncthreads();

    float acc[4][NO];
    #pragma unroll
    for (int r = 0; r < 4; ++r)
        #pragma unroll
        for (int o = 0; o < NO; ++o) acc[r][o] = 0.f;

    if (lane < WW) {
        #pragma unroll
        for (int ci = 0; ci < 2; ++ci) {
            const int cl = wv * 2 + ci;
            const int c  = c0 + cl;
            const float* xc = x + ((long)b * CC + c) * HH * WW;
            // rolling 6-row tap buffer: rows h0-1 .. h0+4
            float xr[6][3];
            #pragma unroll
            for (int r6 = 0; r6 < 6; ++r6) {
                const int hy = h0 + r6 - 1;
                float v0 = 0.f, v1 = 0.f, v2 = 0.f;
                if (hy >= 0 && hy < HH) {
                    const float* row = xc + hy * WW;
                    v1 = row[lane];
                    v0 = (lane > 0)      ? row[lane - 1] : 0.f;
                    v2 = (lane < WW - 1) ? row[lane + 1] : 0.f;
                }
                xr[r6][0] = v0; xr[r6][1] = v1; xr[r6][2] = v2;
            }
            #pragma unroll
            for (int ky = 0; ky < 3; ++ky) {
                const float4* wq = (const float4*)&s_wt[cl][ky * 56]; // uniform
                #pragma unroll
                for (int q = 0; q < 14; ++q) {
                    const float4 w4 = wq[q];       // broadcast ds_read_b128
                    #pragma unroll
                    for (int e = 0; e < 4; ++e) {
                        const int f = q * 4 + e;
                        if (f >= 54) break;
                        const float wf = (e == 0) ? w4.x : (e == 1) ? w4.y
                                        : (e == 2) ? w4.z : w4.w;
                        const int o = f / 3, kx = f - o * 3;
                        #pragma unroll
                        for (int r = 0; r < 4; ++r)
                            acc[r][o] += wf * xr[r + ky][kx];
                    }
                }
            }
        }
    }

    // cross-wave reduce, 1 row per round (keeps LDS small -> 4 blocks/CU)
    const float* sr = (const float*)s_red;    // 4 slices of 1152
    #pragma unroll
    for (int round = 0; round < 4; ++round) {
        __syncthreads();
        #pragma unroll
        for (int o = 0; o < NO; ++o) s_red[wv][o][lane] = acc[round][o];
        __syncthreads();
        const int bh = b * HH + h0 + round;
        float* dst = wsA + ((long)bh * NCG + cg) * (NO * W64);
        for (int s = t; s < NO * W64; s += 256)
            dst[s] = sr[s] + sr[1152 + s] + sr[2 * 1152 + s] + sr[3 * 1152 + s];
    }
}

// ---------------- Kernel A2: reduce 16 partials -> bilinear coefs ----------
__global__ __launch_bounds__(64) void coef_kernel(
    const float* __restrict__ wsA,
    const float* __restrict__ offset_b,
    float4* __restrict__ wsC,
    unsigned* __restrict__ wsI)
{
    const int blk = blockIdx.x;          // bh*9 + k2
    const int k2  = blk % NK2;
    const int bh  = blk / NK2;
    const int b   = bh / HH;
    const int h   = bh - b * HH;
    const int w   = threadIdx.x;         // 0..63

    const float* base = wsA + (long)bh * (NCG * NO * W64);
    float dy = offset_b[2 * k2];
    float dx = offset_b[2 * k2 + 1];
    #pragma unroll
    for (int g = 0; g < NCG; ++g) {
        dy += base[g * (NO * W64) + (2 * k2) * W64 + w];
        dx += base[g * (NO * W64) + (2 * k2 + 1) * W64 + w];
    }

    const float yc = dy + 0.5f + (float)(k2 / 3);
    const float xc = dx + 0.5f + (float)(k2 % 3);
    const float y0 = floorf(yc), x0f = floorf(xc);
    const float fy = yc - y0, fx = xc - x0f;
    const int yi = (int)y0, xi = (int)x0f;
    float cf[4]; int id[4];
    #pragma unroll
    for (int q = 0; q < 4; ++q) {
        const int oy = q >> 1, ox = q & 1;
        const int yy = yi + oy, xx = xi + ox;
        float c2 = (oy ? fy : 1.f - fy) * (ox ? fx : 1.f - fx);
        const bool valid = (yy >= 0) && (yy < WSZ) && (xx >= 0) && (xx < WSZ);
        cf[q] = valid ? c2 : 0.f;
        const int yyc = yy < 0 ? 0 : (yy > 3 ? 3 : yy);
        const int xxc = xx < 0 ? 0 : (xx > 3 ? 3 : xx);
        id[q] = yyc * 4 + xxc;
    }
    const long oidx = ((long)(b * NK2 + k2) * HH + h) * W64 + w;
    wsC[oidx] = make_float4(cf[0], cf[1], cf[2], cf[3]);
    wsI[oidx] = (unsigned)(id[0] | (id[1] << 4) | (id[2] << 8) | (id[3] << 12));
}

// ---------------- Kernel B: weight sampling + patch multiply ---------------
__global__ __launch_bounds__(256) void sample_kernel(
    const float* __restrict__ x,        // [B][C][H][W]
    const float* __restrict__ weight,   // [C][16]
    const float4* __restrict__ wsC,
    const unsigned* __restrict__ wsI,
    float* __restrict__ out)            // [B][C][H][W]
{
    const int blk = blockIdx.x;          // bh*8 + cg
    const int bh  = blk >> 3;
    const int cg  = blk & 7;
    const int b   = bh / HH;
    const int h   = bh - b * HH;
    const int t   = threadIdx.x;
    const int lane = t & 63;
    const int wv  = __builtin_amdgcn_readfirstlane(t >> 6);  // 0..3

    __shared__ float s_wT[16][20];       // [j][c], pad 16->20
    if (t < 256) {
        const int j = t >> 4, cl = t & 15;
        s_wT[j][cl] = weight[(cg * CPG + cl) * 16 + j];
    }
    __syncthreads();

    if (lane >= WW) return;
    const int w = lane;
    const int cl0 = wv * 4;

    float4 cf[NK2]; unsigned pk[NK2];
    const long cidx0 = ((long)b * NK2 * HH + h) * W64 + w;
    #pragma unroll
    for (int k2 = 0; k2 < NK2; ++k2) {
        cf[k2] = wsC[cidx0 + (long)k2 * HH * W64];
        pk[k2] = wsI[cidx0 + (long)k2 * HH * W64];
    }

    float xv[4][9];
    #pragma unroll
    for (int u = 0; u < 4; ++u) {
        const int c = cg * CPG + cl0 + u;
        const float* xc = x + ((long)b * CC + c) * HH * WW;
        #pragma unroll
        for (int ky = 0; ky < 3; ++ky) {
            const int hy = h + ky - 1;
            #pragma unroll
            for (int kx = 0; kx < 3; ++kx) {
                const int wx = w + kx - 1;
                float v = 0.f;
                if (hy >= 0 && hy < HH && wx >= 0 && wx < WW)
                    v = xc[hy * WW + wx];
                xv[u][ky * 3 + kx] = v;
            }
        }
    }

    float res[4] = {0.f, 0.f, 0.f, 0.f};
    #pragma unroll
    for (int k2 = 0; k2 < NK2; ++k2) {
        const unsigned p = pk[k2];
        const float4 W0 = *(const float4*)&s_wT[p & 15][cl0];
        const float4 W1 = *(const float4*)&s_wT[(p >> 4) & 15][cl0];
        const float4 W2 = *(const float4*)&s_wT[(p >> 8) & 15][cl0];
        const float4 W3 = *(const float4*)&s_wT[(p >> 12) & 15][cl0];
        const float4 c4 = cf[k2];
        res[0] += (c4.x * W0.x + c4.y * W1.x + c4.z * W2.x + c4.w * W3.x) * xv[0][k2];
        res[1] += (c4.x * W0.y + c4.y * W1.y + c4.z * W2.y + c4.w * W3.y) * xv[1][k2];
        res[2] += (c4.x * W0.z + c4.y * W1.z + c4.z * W2.z + c4.w * W3.z) * xv[2][k2];
        res[3] += (c4.x * W0.w + c4.y * W1.w + c4.z * W2.w + c4.w * W3.w) * xv[3][k2];
    }

    #pragma unroll
    for (int u = 0; u < 4; ++u) {
        const int c = cg * CPG + cl0 + u;
        out[(((long)b * CC + c) * HH + h) * WW + w] = res[u];
    }
}

extern "C" void kernel_launch(void* const* d_in, const int* in_sizes, int n_in,
                              void* d_out, int out_size, void* d_ws, size_t ws_size,
                              hipStream_t stream) {
    const float* x        = (const float*)d_in[0];
    const float* offset_w = (const float*)d_in[1];
    const float* offset_b = (const float*)d_in[2];
    const float* weight   = (const float*)d_in[3];
    float* out = (float*)d_out;

    char* p = (char*)d_ws;
    float*    wsA = (float*)p;                          p += WSA_FLOATS * 4;
    float4*   wsC = (float4*)p;                         p += WSC_ENTRIES * 16;
    unsigned* wsI = (unsigned*)p;

    conv_partial <<<4 * 14 * NCG, 256, 0, stream>>>(x, offset_w, wsA);
    coef_kernel  <<<224 * NK2, 64, 0, stream>>>(wsA, offset_b, wsC, wsI);
    sample_kernel<<<224 * SCG, 256, 0, stream>>>(x, weight, wsC, wsI, out);
}

// Round 7
// 95.410 us; speedup vs baseline: 1.3964x; 1.3964x over previous
//
#include <hip/hip_runtime.h>

#define CC 128
#define HH 56
#define WW 56
#define NK2 9
#define NO 18
#define WSZ 4
#define W64 64
#define NCG 16     // conv channel groups (8 ch each)
#define SCG 8      // sample channel groups (16 ch each)
#define CPG 16

// ws layout:
//  wsA : float [4*56][NCG][NO][W64]  = 16.5 MB
//  wsC : float4 [4][9][56][W64]      = 2.06 MB
//  wsI : uint   [4][9][56][W64]      = 0.52 MB
#define WSA_FLOATS (224L * NCG * NO * W64)
#define WSC_ENTRIES (4L * NK2 * HH * W64)

// ---------------- Kernel A: offset conv, 4 rows/block, weights in SGPR -----
// block = (b, h4, cg: 8 ch); wave = 2 channels. Weights read DIRECTLY from
// offset_w with wave-uniform addresses, o-outer so each (c,o) is 9 contiguous
// floats -> merged s_load_dwordx8 (SGPRs, zero VGPR cost). 9 weights
// amortized over 4 output rows.
__global__ __launch_bounds__(256, 4) void conv_partial(
    const float* __restrict__ x,          // [B][C][H][W]
    const float* __restrict__ offset_w,   // [18][128][3][3]
    float* __restrict__ wsA)
{
    const int blk = blockIdx.x;           // (b*14 + h4)*16 + cg
    const int cg  = blk & 15;
    const int bh4 = blk >> 4;
    const int b   = bh4 / 14;
    const int h4  = bh4 - b * 14;
    const int h0  = h4 * 4;
    const int t   = threadIdx.x;
    const int lane = t & 63;
    const int wv  = __builtin_amdgcn_readfirstlane(t >> 6);   // 0..3

    __shared__ float s_red[4][2][NO][W64];    // 36 KiB

    float acc[4][NO];
    #pragma unroll
    for (int r = 0; r < 4; ++r)
        #pragma unroll
        for (int o = 0; o < NO; ++o) acc[r][o] = 0.f;

    if (lane < WW) {
        #pragma unroll
        for (int ci = 0; ci < 2; ++ci) {
            const int c = cg * 8 + wv * 2 + ci;   // wave-uniform
            const float* xc = x + ((long)b * CC + c) * HH * WW;
            // rolling 6-row tap buffer: rows h0-1 .. h0+4
            float xr[6][3];
            #pragma unroll
            for (int r6 = 0; r6 < 6; ++r6) {
                const int hy = h0 + r6 - 1;
                float v0 = 0.f, v1 = 0.f, v2 = 0.f;
                if (hy >= 0 && hy < HH) {
                    const float* row = xc + hy * WW;
                    v1 = row[lane];
                    v0 = (lane > 0)      ? row[lane - 1] : 0.f;
                    v2 = (lane < WW - 1) ? row[lane + 1] : 0.f;
                }
                xr[r6][0] = v0; xr[r6][1] = v1; xr[r6][2] = v2;
            }
            const float* wc = offset_w + c * 9;   // wave-uniform base
            #pragma unroll
            for (int o = 0; o < NO; ++o) {
                const float* wo = wc + o * (CC * 9);  // 9 contiguous floats
                float w9[9];
                #pragma unroll
                for (int j = 0; j < 9; ++j) w9[j] = wo[j];  // s_load_dwordx8+1
                #pragma unroll
                for (int ky = 0; ky < 3; ++ky)
                    #pragma unroll
                    for (int kx = 0; kx < 3; ++kx) {
                        const float wf = w9[ky * 3 + kx];
                        #pragma unroll
                        for (int r = 0; r < 4; ++r)
                            acc[r][o] += wf * xr[r + ky][kx];
                    }
            }
        }
    }

    // cross-wave reduce, 2 rows per round (LDS 36 KB)
    const float* sr = (const float*)s_red;        // 4 slices of 2304
    #pragma unroll
    for (int round = 0; round < 2; ++round) {
        #pragma unroll
        for (int r2 = 0; r2 < 2; ++r2)
            #pragma unroll
            for (int o = 0; o < NO; ++o)
                s_red[wv][r2][o][lane] = acc[round * 2 + r2][o];
        __syncthreads();
        for (int s = t; s < 2 * NO * W64; s += 256) {
            const float v = sr[s] + sr[2304 + s] + sr[2 * 2304 + s] + sr[3 * 2304 + s];
            const int r2  = s / (NO * W64);
            const int rem = s - r2 * (NO * W64);
            const int bh  = b * HH + h0 + round * 2 + r2;
            wsA[((long)bh * NCG + cg) * (NO * W64) + rem] = v;
        }
        __syncthreads();
    }
}

// ---------------- Kernel A2: reduce 16 partials -> bilinear coefs ----------
__global__ __launch_bounds__(64) void coef_kernel(
    const float* __restrict__ wsA,
    const float* __restrict__ offset_b,
    float4* __restrict__ wsC,
    unsigned* __restrict__ wsI)
{
    const int blk = blockIdx.x;          // bh*9 + k2
    const int k2  = blk % NK2;
    const int bh  = blk / NK2;
    const int b   = bh / HH;
    const int h   = bh - b * HH;
    const int w   = threadIdx.x;         // 0..63

    const float* base = wsA + (long)bh * (NCG * NO * W64);
    float dy = offset_b[2 * k2];
    float dx = offset_b[2 * k2 + 1];
    #pragma unroll
    for (int g = 0; g < NCG; ++g) {
        dy += base[g * (NO * W64) + (2 * k2) * W64 + w];
        dx += base[g * (NO * W64) + (2 * k2 + 1) * W64 + w];
    }

    const float yc = dy + 0.5f + (float)(k2 / 3);
    const float xc = dx + 0.5f + (float)(k2 % 3);
    const float y0 = floorf(yc), x0f = floorf(xc);
    const float fy = yc - y0, fx = xc - x0f;
    const int yi = (int)y0, xi = (int)x0f;
    float cf[4]; int id[4];
    #pragma unroll
    for (int q = 0; q < 4; ++q) {
        const int oy = q >> 1, ox = q & 1;
        const int yy = yi + oy, xx = xi + ox;
        float c2 = (oy ? fy : 1.f - fy) * (ox ? fx : 1.f - fx);
        const bool valid = (yy >= 0) && (yy < WSZ) && (xx >= 0) && (xx < WSZ);
        cf[q] = valid ? c2 : 0.f;
        const int yyc = yy < 0 ? 0 : (yy > 3 ? 3 : yy);
        const int xxc = xx < 0 ? 0 : (xx > 3 ? 3 : xx);
        id[q] = yyc * 4 + xxc;
    }
    const long oidx = ((long)(b * NK2 + k2) * HH + h) * W64 + w;
    wsC[oidx] = make_float4(cf[0], cf[1], cf[2], cf[3]);
    wsI[oidx] = (unsigned)(id[0] | (id[1] << 4) | (id[2] << 8) | (id[3] << 12));
}

// ---------------- Kernel B: weight sampling + patch multiply ---------------
__global__ __launch_bounds__(256) void sample_kernel(
    const float* __restrict__ x,        // [B][C][H][W]
    const float* __restrict__ weight,   // [C][16]
    const float4* __restrict__ wsC,
    const unsigned* __restrict__ wsI,
    float* __restrict__ out)            // [B][C][H][W]
{
    const int blk = blockIdx.x;          // bh*8 + cg
    const int bh  = blk >> 3;
    const int cg  = blk & 7;
    const int b   = bh / HH;
    const int h   = bh - b * HH;
    const int t   = threadIdx.x;
    const int lane = t & 63;
    const int wv  = __builtin_amdgcn_readfirstlane(t >> 6);  // 0..3

    __shared__ float s_wT[16][20];       // [j][c], pad 16->20
    if (t < 256) {
        const int j = t >> 4, cl = t & 15;
        s_wT[j][cl] = weight[(cg * CPG + cl) * 16 + j];
    }
    __syncthreads();

    if (lane >= WW) return;
    const int w = lane;
    const int cl0 = wv * 4;

    float4 cf[NK2]; unsigned pk[NK2];
    const long cidx0 = ((long)b * NK2 * HH + h) * W64 + w;
    #pragma unroll
    for (int k2 = 0; k2 < NK2; ++k2) {
        cf[k2] = wsC[cidx0 + (long)k2 * HH * W64];
        pk[k2] = wsI[cidx0 + (long)k2 * HH * W64];
    }

    float xv[4][9];
    #pragma unroll
    for (int u = 0; u < 4; ++u) {
        const int c = cg * CPG + cl0 + u;
        const float* xc = x + ((long)b * CC + c) * HH * WW;
        #pragma unroll
        for (int ky = 0; ky < 3; ++ky) {
            const int hy = h + ky - 1;
            #pragma unroll
            for (int kx = 0; kx < 3; ++kx) {
                const int wx = w + kx - 1;
                float v = 0.f;
                if (hy >= 0 && hy < HH && wx >= 0 && wx < WW)
                    v = xc[hy * WW + wx];
                xv[u][ky * 3 + kx] = v;
            }
        }
    }

    float res[4] = {0.f, 0.f, 0.f, 0.f};
    #pragma unroll
    for (int k2 = 0; k2 < NK2; ++k2) {
        const unsigned p = pk[k2];
        const float4 W0 = *(const float4*)&s_wT[p & 15][cl0];
        const float4 W1 = *(const float4*)&s_wT[(p >> 4) & 15][cl0];
        const float4 W2 = *(const float4*)&s_wT[(p >> 8) & 15][cl0];
        const float4 W3 = *(const float4*)&s_wT[(p >> 12) & 15][cl0];
        const float4 c4 = cf[k2];
        res[0] += (c4.x * W0.x + c4.y * W1.x + c4.z * W2.x + c4.w * W3.x) * xv[0][k2];
        res[1] += (c4.x * W0.y + c4.y * W1.y + c4.z * W2.y + c4.w * W3.y) * xv[1][k2];
        res[2] += (c4.x * W0.z + c4.y * W1.z + c4.z * W2.z + c4.w * W3.z) * xv[2][k2];
        res[3] += (c4.x * W0.w + c4.y * W1.w + c4.z * W2.w + c4.w * W3.w) * xv[3][k2];
    }

    #pragma unroll
    for (int u = 0; u < 4; ++u) {
        const int c = cg * CPG + cl0 + u;
        out[(((long)b * CC + c) * HH + h) * WW + w] = res[u];
    }
}

extern "C" void kernel_launch(void* const* d_in, const int* in_sizes, int n_in,
                              void* d_out, int out_size, void* d_ws, size_t ws_size,
                              hipStream_t stream) {
    const float* x        = (const float*)d_in[0];
    const float* offset_w = (const float*)d_in[1];
    const float* offset_b = (const float*)d_in[2];
    const float* weight   = (const float*)d_in[3];
    float* out = (float*)d_out;

    char* p = (char*)d_ws;
    float*    wsA = (float*)p;                          p += WSA_FLOATS * 4;
    float4*   wsC = (float4*)p;                         p += WSC_ENTRIES * 16;
    unsigned* wsI = (unsigned*)p;

    conv_partial <<<4 * 14 * NCG, 256, 0, stream>>>(x, offset_w, wsA);
    coef_kernel  <<<224 * NK2, 64, 0, stream>>>(wsA, offset_b, wsC, wsI);
    sample_kernel<<<224 * SCG, 256, 0, stream>>>(x, weight, wsC, wsI, out);
}